// Round 7
// baseline (903.205 us; speedup 1.0000x reference)
//
#include <hip/hip_runtime.h>
#include <hip/hip_bf16.h>
#include <math.h>

#define B 32
#define CFULL 12
#define CH 6
#define HH 128
#define WW 128
#define HID 128
#define CO3 54
#define NB 5
#define OUT_ELEMS (B*CFULL*HH*WW)
#define H2_BYTES (size_t)(B*HH*WW*HID*2)        // bf16 channels-last [b][h][w][ci]
#define WFRAG_ELEMS (9*4*4*64*8)                 // w3 frags: 73728 bf16
#define W1F_ELEMS (2*8*64*8)                     // 8192
#define W2F_ELEMS (4*8*64*8)                     // 16384

typedef __bf16 bf16x8 __attribute__((ext_vector_type(8)));
typedef float f32x4 __attribute__((ext_vector_type(4)));

__device__ __forceinline__ ushort f2bf(float f) {
    uint b = __float_as_uint(f);
    uint r = (b + 0x7FFFu + ((b >> 16) & 1u)) >> 16;
    return (ushort)r;
}

union UBF { uint4 u; bf16x8 b; };

// ---------------- combined prep: objective copy + w1/w2/w3 fragment layouts ----------------
__global__ __launch_bounds__(256) void k_prep_all(
    const float* __restrict__ w1, const float* __restrict__ w2, const float* __restrict__ w3,
    const float* __restrict__ obj_in, float* __restrict__ obj_out,
    ushort* __restrict__ W1f, ushort* __restrict__ W2f, ushort* __restrict__ W3f)
{
    int idx = blockIdx.x * 256 + threadIdx.x;
    if (blockIdx.x == 0 && threadIdx.x < B) obj_out[threadIdx.x] = obj_in[threadIdx.x];

    if (idx < WFRAG_ELEMS) {
        int j    = idx & 7;
        int lane = (idx >> 3) & 63;
        int nf   = (idx >> 9) & 3;
        int kb   = (idx >> 11) & 3;
        int t    = idx >> 13;
        int co = nf * 16 + (lane & 15);
        int ci = kb * 32 + 8 * (lane >> 4) + j;
        float v = (co < CO3) ? w3[(co * HID + ci) * 9 + t] : 0.f;
        W3f[idx] = f2bf(v);
    } else if (idx < WFRAG_ELEMS + W1F_ELEMS) {
        int i1 = idx - WFRAG_ELEMS;
        int j = i1 & 7, lane = (i1 >> 3) & 63, nf = (i1 >> 9) & 7, ks = i1 >> 12;
        int co = nf * 16 + (lane & 15);
        int k  = ks * 32 + (lane >> 4) * 8 + j;
        W1f[i1] = f2bf(k < 54 ? w1[co * 54 + k] : 0.f);
    } else if (idx < WFRAG_ELEMS + W1F_ELEMS + W2F_ELEMS) {
        int i2 = idx - WFRAG_ELEMS - W1F_ELEMS;
        int j = i2 & 7, lane = (i2 >> 3) & 63, nf = (i2 >> 9) & 7, ks = (i2 >> 12) & 3;
        int co = nf * 16 + (lane & 15);
        int ci = ks * 32 + (lane >> 4) * 8 + j;
        W2f[i2] = f2bf(w2[co * 128 + ci]);
    }
}

// ---------------- conv1+conv2 via MFMA, writes h2 bf16 channels-last ----------------
// LDS fully overlaid: {xs+A} -> h1 -> h2st, 32KB total => 5 blocks/CU
__global__ __launch_bounds__(256, 5) void k_conv12(
    const float* __restrict__ x,
    const ushort* __restrict__ W1f, const float* __restrict__ b1,
    const ushort* __restrict__ W2f, const float* __restrict__ b2,
    ushort* __restrict__ h2)
{
    __shared__ char buf[32768];

    ushort* xs = (ushort*)buf;                // [6][3][132] bf16 (4752B)
    char* Albase = buf + 4864;                // A [128px][64k] bf16 swizzled (16KB, ends 21248)
    char* h1 = buf;                           // overlays xs+A after conv1
    char* h2st = buf;                         // overlays h1 after conv2

    const int b = blockIdx.x >> 7;
    const int h = blockIdx.x & 127;
    const int tid = threadIdx.x;
    const int lane = tid & 63;
    const int wv = tid >> 6;        // 0..3
    const int lr = lane & 15;
    const int kg = lane >> 4;       // 0..3

    // ---- stage x rows: 6ch x 3r x 130w (as bf16) ----
    for (int i = tid; i < 6*3*130; i += 256) {
        int ci = i / 390; int rem = i - ci*390;
        int r = rem / 130; int xw = rem - r*130;
        int hh = h + r - 1, ww = xw - 1;
        float v = 0.f;
        if (hh >= 0 && hh < HH && ww >= 0 && ww < WW)
            v = x[((b*CFULL + ci)*HH + hh)*WW + ww];
        xs[(ci*3 + r)*132 + xw] = f2bf(v);
    }
    __syncthreads();

    // ---- build im2col A: [128px][64k], k = ci*9 + r*3 + dx (54 used) ----
    for (int it = 0; it < 4; ++it) {
        int item = (it << 8) + tid;          // 1024 items
        int px = item & 127;
        int g  = item >> 7;                  // 0..7
        uint pk[4];
#pragma unroll
        for (int jj = 0; jj < 4; ++jj) {
            int k0 = g*8 + jj*2;
            int k1 = k0 + 1;
            uint v0 = 0, v1 = 0;
            if (k0 < 54) { int ci = k0/9; int rem = k0 - ci*9; int r = rem/3; int dx = rem - r*3;
                           v0 = xs[(ci*3 + r)*132 + px + dx]; }
            if (k1 < 54) { int ci = k1/9; int rem = k1 - ci*9; int r = rem/3; int dx = rem - r*3;
                           v1 = xs[(ci*3 + r)*132 + px + dx]; }
            pk[jj] = v0 | (v1 << 16);
        }
        uint4 q; q.x = pk[0]; q.y = pk[1]; q.z = pk[2]; q.w = pk[3];
        *(uint4*)(Albase + px*128 + ((g << 4) ^ (((px >> 1) & 7) << 4))) = q;
    }
    __syncthreads();

    // ---- conv1 MFMA: M=32px/wave, N=128, K=64 ----
    f32x4 acc[2][8];
#pragma unroll
    for (int mm = 0; mm < 2; ++mm)
#pragma unroll
        for (int nf = 0; nf < 8; ++nf) acc[mm][nf] = (f32x4){0.f,0.f,0.f,0.f};

    const int px0 = wv*32 + lr;
    const int px1 = px0 + 16;
#pragma unroll
    for (int ks = 0; ks < 2; ++ks) {
        UBF a0, a1;
        a0.u = *(const uint4*)(Albase + px0*128 + ((ks*64 + kg*16) ^ (((px0 >> 1) & 7) << 4)));
        a1.u = *(const uint4*)(Albase + px1*128 + ((ks*64 + kg*16) ^ (((px1 >> 1) & 7) << 4)));
        const char* wp = (const char*)W1f + ks*8192 + lane*16;
#pragma unroll
        for (int nf = 0; nf < 8; ++nf) {
            UBF bf; bf.u = *(const uint4*)(wp + nf*1024);
            acc[0][nf] = __builtin_amdgcn_mfma_f32_16x16x32_bf16(a0.b, bf.b, acc[0][nf], 0, 0, 0);
            acc[1][nf] = __builtin_amdgcn_mfma_f32_16x16x32_bf16(a1.b, bf.b, acc[1][nf], 0, 0, 0);
        }
    }
    __syncthreads();   // all A reads done before h1 overlays xs+A

    // ---- h1 = relu(conv1+b1) -> LDS [px][co] bf16 swizzled (overlays xs+A) ----
    float b1v[8];
#pragma unroll
    for (int nf = 0; nf < 8; ++nf) b1v[nf] = b1[nf*16 + lr];
#pragma unroll
    for (int mm = 0; mm < 2; ++mm)
#pragma unroll
        for (int nf = 0; nf < 8; ++nf) {
            int co2 = (nf*16 + lr) * 2;
#pragma unroll
            for (int rg = 0; rg < 4; ++rg) {
                int px = wv*32 + mm*16 + kg*4 + rg;
                float v = fmaxf(acc[mm][nf][rg] + b1v[nf], 0.f);
                *(ushort*)(h1 + px*256 + (co2 ^ (((px >> 1) & 7) << 4))) = f2bf(v);
            }
        }
    __syncthreads();

    // ---- conv2 MFMA: K=128 ----
#pragma unroll
    for (int mm = 0; mm < 2; ++mm)
#pragma unroll
        for (int nf = 0; nf < 8; ++nf) acc[mm][nf] = (f32x4){0.f,0.f,0.f,0.f};
#pragma unroll
    for (int ks = 0; ks < 4; ++ks) {
        UBF a0, a1;
        a0.u = *(const uint4*)(h1 + px0*256 + ((ks*64 + kg*16) ^ (((px0 >> 1) & 7) << 4)));
        a1.u = *(const uint4*)(h1 + px1*256 + ((ks*64 + kg*16) ^ (((px1 >> 1) & 7) << 4)));
        const char* wp = (const char*)W2f + ks*8192 + lane*16;
#pragma unroll
        for (int nf = 0; nf < 8; ++nf) {
            UBF bf; bf.u = *(const uint4*)(wp + nf*1024);
            acc[0][nf] = __builtin_amdgcn_mfma_f32_16x16x32_bf16(a0.b, bf.b, acc[0][nf], 0, 0, 0);
            acc[1][nf] = __builtin_amdgcn_mfma_f32_16x16x32_bf16(a1.b, bf.b, acc[1][nf], 0, 0, 0);
        }
    }
    __syncthreads();   // all h1 reads done before h2st overlays

    // ---- h2 = relu(conv2+b2) -> staging LDS (swizzled) ----
    float b2v[8];
#pragma unroll
    for (int nf = 0; nf < 8; ++nf) b2v[nf] = b2[nf*16 + lr];
#pragma unroll
    for (int mm = 0; mm < 2; ++mm)
#pragma unroll
        for (int nf = 0; nf < 8; ++nf) {
            int co2 = (nf*16 + lr) * 2;
#pragma unroll
            for (int rg = 0; rg < 4; ++rg) {
                int px = wv*32 + mm*16 + kg*4 + rg;
                float v = fmaxf(acc[mm][nf][rg] + b2v[nf], 0.f);
                *(ushort*)(h2st + px*256 + (co2 ^ (((px >> 1) & 7) << 4))) = f2bf(v);
            }
        }
    __syncthreads();

    // ---- coalesced copy: 32KB tile is contiguous in h2 ----
    const size_t outbase = (size_t)((b*HH + h)*WW) * HID;
    for (int c = tid; c < 2048; c += 256) {
        int px = c >> 4; int cb = (c & 15) << 4;
        uint4 v = *(const uint4*)(h2st + px*256 + (cb ^ (((px >> 1) & 7) << 4)));
        *(uint4*)&h2[outbase + (size_t)c*8] = v;
    }
}

// ---------------- conv3 (MFMA bf16) + spline + identity copy + objective ----------------
// block: (g = 4-row group, b); 512 thr = 8 waves; wave = full row (128px) x 32co
// A-tile: [6 h2rows][132 wl][32 ci] bf16 per ci-quarter, XOR-((wl>>1)&3) swizzle (conflict-free)
__global__ __launch_bounds__(512, 6) void k_conv3_spline(
    const float* __restrict__ x,
    const ushort* __restrict__ h2,
    const ushort* __restrict__ Wfrag, const float* __restrict__ b3,
    float* __restrict__ out, float* __restrict__ obj)
{
    __shared__ char xsb[50688];         // 6*8448; later params pl[64][132] f32 (33792B) overlaid
    __shared__ float red[8];

    const int g = blockIdx.x;           // rows 4g .. 4g+3
    const int b = blockIdx.y;
    const int tid = threadIdx.x;        // 0..511
    const int px = tid & 127;
    const int t7 = tid >> 7;            // 0..3

    // ---- prologue: identity copy + transform-x prefetch (pure HBM) ----
    float xr[4][2];
#pragma unroll
    for (int r = 0; r < 4; ++r) {
        const size_t base = ((size_t)(b*CFULL + t7)*HH + (4*g + r))*WW + px;
        out[base] = x[base];
        xr[r][0] = x[base + (size_t)CH*HH*WW];
        xr[r][1] = 0.f;
        if (tid < 256) {
            const size_t base2 = ((size_t)(b*CFULL + 4 + t7)*HH + (4*g + r))*WW + px;
            out[base2] = x[base2];
            xr[r][1] = x[base2 + (size_t)CH*HH*WW];
        }
    }

    const int lane = tid & 63;
    const int wv   = tid >> 6;          // 0..7
    const int mrow = wv >> 1;           // 0..3 : output row
    const int ncol = wv & 1;            // 0..1 : co half
    const int kg   = lane >> 4;
    const int lr   = lane & 15;

    f32x4 acc[8][2];
#pragma unroll
    for (int mf = 0; mf < 8; ++mf) {
        acc[mf][0] = (f32x4){0.f,0.f,0.f,0.f};
        acc[mf][1] = (f32x4){0.f,0.f,0.f,0.f};
    }

    const char* wbase = (const char*)Wfrag + ncol*2048 + lane*16;

#pragma unroll 1
    for (int q = 0; q < 4; ++q) {
        if (q) __syncthreads();         // protect tile from previous quarter's readers

        // ---- stage quarter: 6 h2-rows x 130 wl x 32 ci ----
        for (int i = tid; i < 3120; i += 512) {
            int r = i / 520; int rem = i - r*520;
            int wl = rem >> 2; int c4 = rem & 3;
            int hh = 4*g - 1 + r, ww = wl - 1;
            uint4 v = {0,0,0,0};
            if (hh >= 0 && hh < HH && ww >= 0 && ww < WW)
                v = *(const uint4*)&h2[(size_t)((b*HH + hh)*WW + ww)*HID + q*32 + c4*8];
            *(uint4*)(xsb + r*8448 + wl*64 + ((c4*16) ^ (((wl >> 1) & 3) << 4))) = v;
        }
        __syncthreads();

        // ---- MFMA: 9 taps, K=32 each ----
#pragma unroll 1
        for (int r3 = 0; r3 < 3; ++r3) {
            const char* rowb = xsb + (mrow + r3)*8448;
#pragma unroll
            for (int dx = 0; dx < 3; ++dx) {
                const int t = r3*3 + dx;
                const char* wp = wbase + (((t << 2) + q) << 12);
                UBF b0; b0.u = *(const uint4*)(wp);
                UBF b1; b1.u = *(const uint4*)(wp + 1024);
#pragma unroll
                for (int mf = 0; mf < 8; ++mf) {
                    const int wl = mf*16 + lr + dx;
                    UBF a; a.u = *(const uint4*)(rowb + wl*64 + ((kg*16) ^ (((wl >> 1) & 3) << 4)));
                    acc[mf][0] = __builtin_amdgcn_mfma_f32_16x16x32_bf16(a.b, b0.b, acc[mf][0], 0, 0, 0);
                    acc[mf][1] = __builtin_amdgcn_mfma_f32_16x16x32_bf16(a.b, b1.b, acc[mf][1], 0, 0, 0);
                }
            }
        }
    }
    __syncthreads();        // A-tile dead; overlay params

    float* pl = (float*)xsb;
    float lad = 0.f;

#pragma unroll
    for (int r = 0; r < 4; ++r) {
        if (r) __syncthreads();         // wait for previous phase's pl readers

        if (mrow == r) {
#pragma unroll
            for (int mf = 0; mf < 8; ++mf)
#pragma unroll
                for (int nf = 0; nf < 2; ++nf) {
                    const int co = ncol*32 + nf*16 + lr;
                    const int p0 = mf*16 + (kg << 2);
                    *(f32x4*)&pl[co*132 + p0] = acc[mf][nf];
                }
        }
        __syncthreads();

        // ---- spline for row 4g+r: 6 ch x 128 px = 768 items ----
#pragma unroll
        for (int s = 0; s < 2; ++s) {
            if (s == 0 || tid < 256) {
                const int c = __builtin_amdgcn_readfirstlane(s ? 4 + t7 : t7);
                const float xraw = xr[r][s];

                float u[9];
#pragma unroll
                for (int j = 0; j < 9; ++j) u[j] = pl[(c*9 + j)*132 + px] + b3[c*9 + j];

                bool inside = (xraw >= -1.f) && (xraw <= 1.f);
                float xc = fminf(fmaxf(xraw, -1.f), 1.f);
                float in01 = (xc + 1.f) * 0.5f;

                float m = u[0];
#pragma unroll
                for (int i2 = 1; i2 < 5; ++i2) m = fmaxf(m, u[i2]);
                float e[5], es = 0.f;
#pragma unroll
                for (int i2 = 0; i2 < 5; ++i2) { e[i2] = expf(u[i2] - m); es += e[i2]; }
                float wdt[5];
#pragma unroll
                for (int i2 = 0; i2 < 5; ++i2) wdt[i2] = 0.001f + (1.f - 0.001f*NB) * (e[i2] / es);

                float eh[4];
#pragma unroll
                for (int i2 = 0; i2 < 4; ++i2) eh[i2] = expf(u[5 + i2]);

                float first_w = 0.5f * wdt[0], last_w = 0.5f * wdt[4];
                float numer = 0.5f*first_w*eh[0] + 0.5f*last_w*eh[3]
                            + 0.5f*(eh[0]+eh[1])*wdt[1]
                            + 0.5f*(eh[1]+eh[2])*wdt[2]
                            + 0.5f*(eh[2]+eh[3])*wdt[3];
                float cst = numer / (1.f - 0.5f*first_w - 0.5f*last_w);

                float kn[6] = {cst, eh[0], eh[1], eh[2], eh[3], cst};
                float area = 0.f;
#pragma unroll
                for (int i2 = 0; i2 < 5; ++i2) area += 0.5f*(kn[i2]+kn[i2+1])*wdt[i2];
                float hts[6];
#pragma unroll
                for (int i2 = 0; i2 < 6; ++i2) hts[i2] = 0.001f + (1.f - 0.001f) * (kn[i2] / area);

                float C[6]; C[0] = 0.f;
#pragma unroll
                for (int i2 = 0; i2 < 5; ++i2) C[i2+1] = C[i2] + 0.5f*(hts[i2]+hts[i2+1])*wdt[i2];
                C[5] = 1.f;
                float L[6]; L[0] = 0.f;
#pragma unroll
                for (int i2 = 0; i2 < 5; ++i2) L[i2+1] = L[i2] + wdt[i2];
                L[5] = 1.f;

                int idx = 0;
#pragma unroll
                for (int i2 = 1; i2 < 6; ++i2) idx += (in01 >= L[i2]) ? 1 : 0;
                idx = min(idx, 4);

                float loc = L[0], cdf = C[0], hl = hts[0], hr = hts[1], wb2 = wdt[0];
#pragma unroll
                for (int i2 = 1; i2 < 5; ++i2) {
                    if (i2 == idx) { loc = L[i2]; cdf = C[i2]; hl = hts[i2]; hr = hts[i2+1]; wb2 = wdt[i2]; }
                }

                float alpha = (in01 - loc) / wb2;
                float aa = 0.5f*(hr - hl)*wb2;
                float bb = hl*wb2;
                float o = fminf(fmaxf(aa*alpha*alpha + bb*alpha + cdf, 0.f), 1.f);
                float sl = logf(alpha*(hr - hl) + hl);
                float outv = o*2.f - 1.f;
                if (!inside) { outv = xraw; sl = 0.f; }
                out[((size_t)(b*CFULL + CH + c)*HH + (4*g + r))*WW + px] = outv;
                lad += sl;
            }
        }
    }

#pragma unroll
    for (int off = 32; off > 0; off >>= 1) lad += __shfl_down(lad, off, 64);
    if ((tid & 63) == 0) red[tid >> 6] = lad;
    __syncthreads();
    if (tid == 0) {
        float s = 0.f;
#pragma unroll
        for (int i = 0; i < 8; ++i) s += red[i];
        atomicAdd(&obj[b], s);
    }
}

extern "C" void kernel_launch(void* const* d_in, const int* in_sizes, int n_in,
                              void* d_out, int out_size, void* d_ws, size_t ws_size,
                              hipStream_t stream) {
    const float* x   = (const float*)d_in[0];
    const float* obj = (const float*)d_in[1];
    const float* w1  = (const float*)d_in[2];
    const float* b1  = (const float*)d_in[3];
    const float* w2  = (const float*)d_in[4];
    const float* b2  = (const float*)d_in[5];
    const float* w3  = (const float*)d_in[6];
    const float* b3  = (const float*)d_in[7];

    float* out_t = (float*)d_out;
    float* obj_o = out_t + OUT_ELEMS;
    ushort* h2  = (ushort*)d_ws;
    ushort* W3f = (ushort*)((char*)d_ws + H2_BYTES);
    ushort* W1f = (ushort*)((char*)d_ws + H2_BYTES + 147456);
    ushort* W2f = (ushort*)((char*)d_ws + H2_BYTES + 147456 + 16384);

    const int prep_items = WFRAG_ELEMS + W1F_ELEMS + W2F_ELEMS;   // 98304
    k_prep_all<<<(prep_items + 255)/256, 256, 0, stream>>>(w1, w2, w3, obj, obj_o, W1f, W2f, W3f);
    k_conv12<<<B*HH, 256, 0, stream>>>(x, W1f, b1, W2f, b2, h2);
    k_conv3_spline<<<dim3(HH/4, B), 512, 0, stream>>>(x, h2, W3f, b3, out_t, obj_o);
}

// Round 8
// 278.145 us; speedup vs baseline: 3.2472x; 3.2472x over previous
//
#include <hip/hip_runtime.h>
#include <hip/hip_bf16.h>
#include <math.h>

#define B 32
#define CFULL 12
#define CH 6
#define HH 128
#define WW 128
#define HID 128
#define CO3 54
#define NB 5
#define OUT_ELEMS (B*CFULL*HH*WW)
#define H2_BYTES (size_t)(B*HH*WW*HID*2)        // bf16 channels-last [b][h][w][ci]
#define WFRAG_ELEMS (9*4*4*64*8)                 // w3 frags: 73728 bf16
#define W1F_ELEMS (2*8*64*8)                     // 8192
#define W2F_ELEMS (4*8*64*8)                     // 16384

typedef __bf16 bf16x8 __attribute__((ext_vector_type(8)));
typedef float f32x4 __attribute__((ext_vector_type(4)));

__device__ __forceinline__ ushort f2bf(float f) {
    uint b = __float_as_uint(f);
    uint r = (b + 0x7FFFu + ((b >> 16) & 1u)) >> 16;
    return (ushort)r;
}

union UBF { uint4 u; bf16x8 b; };

// ---------------- combined prep: objective copy + w1/w2/w3 fragment layouts ----------------
__global__ __launch_bounds__(256) void k_prep_all(
    const float* __restrict__ w1, const float* __restrict__ w2, const float* __restrict__ w3,
    const float* __restrict__ obj_in, float* __restrict__ obj_out,
    ushort* __restrict__ W1f, ushort* __restrict__ W2f, ushort* __restrict__ W3f)
{
    int idx = blockIdx.x * 256 + threadIdx.x;
    if (blockIdx.x == 0 && threadIdx.x < B) obj_out[threadIdx.x] = obj_in[threadIdx.x];

    if (idx < WFRAG_ELEMS) {
        int j    = idx & 7;
        int lane = (idx >> 3) & 63;
        int nf   = (idx >> 9) & 3;
        int kb   = (idx >> 11) & 3;
        int t    = idx >> 13;
        int co = nf * 16 + (lane & 15);
        int ci = kb * 32 + 8 * (lane >> 4) + j;
        float v = (co < CO3) ? w3[(co * HID + ci) * 9 + t] : 0.f;
        W3f[idx] = f2bf(v);
    } else if (idx < WFRAG_ELEMS + W1F_ELEMS) {
        int i1 = idx - WFRAG_ELEMS;
        int j = i1 & 7, lane = (i1 >> 3) & 63, nf = (i1 >> 9) & 7, ks = i1 >> 12;
        int co = nf * 16 + (lane & 15);
        int k  = ks * 32 + (lane >> 4) * 8 + j;
        W1f[i1] = f2bf(k < 54 ? w1[co * 54 + k] : 0.f);
    } else if (idx < WFRAG_ELEMS + W1F_ELEMS + W2F_ELEMS) {
        int i2 = idx - WFRAG_ELEMS - W1F_ELEMS;
        int j = i2 & 7, lane = (i2 >> 3) & 63, nf = (i2 >> 9) & 7, ks = (i2 >> 12) & 3;
        int co = nf * 16 + (lane & 15);
        int ci = ks * 32 + (lane >> 4) * 8 + j;
        W2f[i2] = f2bf(w2[co * 128 + ci]);
    }
}

// ---------------- conv1+conv2 via MFMA, writes h2 bf16 channels-last ----------------
// LDS fully overlaid: {xs+A} -> h1 -> h2st, 32KB total; no VGPR cap (spill risk)
__global__ __launch_bounds__(256) void k_conv12(
    const float* __restrict__ x,
    const ushort* __restrict__ W1f, const float* __restrict__ b1,
    const ushort* __restrict__ W2f, const float* __restrict__ b2,
    ushort* __restrict__ h2)
{
    __shared__ char buf[32768];

    ushort* xs = (ushort*)buf;                // [6][3][132] bf16 (4752B)
    char* Albase = buf + 4864;                // A [128px][64k] bf16 swizzled (16KB, ends 21248)
    char* h1 = buf;                           // overlays xs+A after conv1
    char* h2st = buf;                         // overlays h1 after conv2

    const int b = blockIdx.x >> 7;
    const int h = blockIdx.x & 127;
    const int tid = threadIdx.x;
    const int lane = tid & 63;
    const int wv = tid >> 6;        // 0..3
    const int lr = lane & 15;
    const int kg = lane >> 4;       // 0..3

    // ---- stage x rows: 6ch x 3r x 130w (as bf16) ----
    for (int i = tid; i < 6*3*130; i += 256) {
        int ci = i / 390; int rem = i - ci*390;
        int r = rem / 130; int xw = rem - r*130;
        int hh = h + r - 1, ww = xw - 1;
        float v = 0.f;
        if (hh >= 0 && hh < HH && ww >= 0 && ww < WW)
            v = x[((b*CFULL + ci)*HH + hh)*WW + ww];
        xs[(ci*3 + r)*132 + xw] = f2bf(v);
    }
    __syncthreads();

    // ---- build im2col A: [128px][64k], k = ci*9 + r*3 + dx (54 used) ----
    for (int it = 0; it < 4; ++it) {
        int item = (it << 8) + tid;          // 1024 items
        int px = item & 127;
        int g  = item >> 7;                  // 0..7
        uint pk[4];
#pragma unroll
        for (int jj = 0; jj < 4; ++jj) {
            int k0 = g*8 + jj*2;
            int k1 = k0 + 1;
            uint v0 = 0, v1 = 0;
            if (k0 < 54) { int ci = k0/9; int rem = k0 - ci*9; int r = rem/3; int dx = rem - r*3;
                           v0 = xs[(ci*3 + r)*132 + px + dx]; }
            if (k1 < 54) { int ci = k1/9; int rem = k1 - ci*9; int r = rem/3; int dx = rem - r*3;
                           v1 = xs[(ci*3 + r)*132 + px + dx]; }
            pk[jj] = v0 | (v1 << 16);
        }
        uint4 q; q.x = pk[0]; q.y = pk[1]; q.z = pk[2]; q.w = pk[3];
        *(uint4*)(Albase + px*128 + ((g << 4) ^ (((px >> 1) & 7) << 4))) = q;
    }
    __syncthreads();

    // ---- conv1 MFMA: M=32px/wave, N=128, K=64 ----
    f32x4 acc[2][8];
#pragma unroll
    for (int mm = 0; mm < 2; ++mm)
#pragma unroll
        for (int nf = 0; nf < 8; ++nf) acc[mm][nf] = (f32x4){0.f,0.f,0.f,0.f};

    const int px0 = wv*32 + lr;
    const int px1 = px0 + 16;
#pragma unroll
    for (int ks = 0; ks < 2; ++ks) {
        UBF a0, a1;
        a0.u = *(const uint4*)(Albase + px0*128 + ((ks*64 + kg*16) ^ (((px0 >> 1) & 7) << 4)));
        a1.u = *(const uint4*)(Albase + px1*128 + ((ks*64 + kg*16) ^ (((px1 >> 1) & 7) << 4)));
        const char* wp = (const char*)W1f + ks*8192 + lane*16;
#pragma unroll
        for (int nf = 0; nf < 8; ++nf) {
            UBF bf; bf.u = *(const uint4*)(wp + nf*1024);
            acc[0][nf] = __builtin_amdgcn_mfma_f32_16x16x32_bf16(a0.b, bf.b, acc[0][nf], 0, 0, 0);
            acc[1][nf] = __builtin_amdgcn_mfma_f32_16x16x32_bf16(a1.b, bf.b, acc[1][nf], 0, 0, 0);
        }
    }
    __syncthreads();   // all A reads done before h1 overlays xs+A

    // ---- h1 = relu(conv1+b1) -> LDS [px][co] bf16 swizzled (overlays xs+A) ----
    float b1v[8];
#pragma unroll
    for (int nf = 0; nf < 8; ++nf) b1v[nf] = b1[nf*16 + lr];
#pragma unroll
    for (int mm = 0; mm < 2; ++mm)
#pragma unroll
        for (int nf = 0; nf < 8; ++nf) {
            int co2 = (nf*16 + lr) * 2;
#pragma unroll
            for (int rg = 0; rg < 4; ++rg) {
                int px = wv*32 + mm*16 + kg*4 + rg;
                float v = fmaxf(acc[mm][nf][rg] + b1v[nf], 0.f);
                *(ushort*)(h1 + px*256 + (co2 ^ (((px >> 1) & 7) << 4))) = f2bf(v);
            }
        }
    __syncthreads();

    // ---- conv2 MFMA: K=128 ----
#pragma unroll
    for (int mm = 0; mm < 2; ++mm)
#pragma unroll
        for (int nf = 0; nf < 8; ++nf) acc[mm][nf] = (f32x4){0.f,0.f,0.f,0.f};
#pragma unroll
    for (int ks = 0; ks < 4; ++ks) {
        UBF a0, a1;
        a0.u = *(const uint4*)(h1 + px0*256 + ((ks*64 + kg*16) ^ (((px0 >> 1) & 7) << 4)));
        a1.u = *(const uint4*)(h1 + px1*256 + ((ks*64 + kg*16) ^ (((px1 >> 1) & 7) << 4)));
        const char* wp = (const char*)W2f + ks*8192 + lane*16;
#pragma unroll
        for (int nf = 0; nf < 8; ++nf) {
            UBF bf; bf.u = *(const uint4*)(wp + nf*1024);
            acc[0][nf] = __builtin_amdgcn_mfma_f32_16x16x32_bf16(a0.b, bf.b, acc[0][nf], 0, 0, 0);
            acc[1][nf] = __builtin_amdgcn_mfma_f32_16x16x32_bf16(a1.b, bf.b, acc[1][nf], 0, 0, 0);
        }
    }
    __syncthreads();   // all h1 reads done before h2st overlays

    // ---- h2 = relu(conv2+b2) -> staging LDS (swizzled) ----
    float b2v[8];
#pragma unroll
    for (int nf = 0; nf < 8; ++nf) b2v[nf] = b2[nf*16 + lr];
#pragma unroll
    for (int mm = 0; mm < 2; ++mm)
#pragma unroll
        for (int nf = 0; nf < 8; ++nf) {
            int co2 = (nf*16 + lr) * 2;
#pragma unroll
            for (int rg = 0; rg < 4; ++rg) {
                int px = wv*32 + mm*16 + kg*4 + rg;
                float v = fmaxf(acc[mm][nf][rg] + b2v[nf], 0.f);
                *(ushort*)(h2st + px*256 + (co2 ^ (((px >> 1) & 7) << 4))) = f2bf(v);
            }
        }
    __syncthreads();

    // ---- coalesced copy: 32KB tile is contiguous in h2 ----
    const size_t outbase = (size_t)((b*HH + h)*WW) * HID;
    for (int c = tid; c < 2048; c += 256) {
        int px = c >> 4; int cb = (c & 15) << 4;
        uint4 v = *(const uint4*)(h2st + px*256 + (cb ^ (((px >> 1) & 7) << 4)));
        *(uint4*)&h2[outbase + (size_t)c*8] = v;
    }
}

// ---------------- conv3 (MFMA bf16) + spline + identity copy + objective ----------------
// block: (row-pair g, b); 256 thr = 4 waves; wave = full row (128px) x 32co
// A-tile: [4 h2rows][132 wl][32 ci] bf16 per ci-quarter, XOR-((wl>>1)&3) swizzle (2-way max)
__global__ __launch_bounds__(256, 3) void k_conv3_spline(
    const float* __restrict__ x,
    const ushort* __restrict__ h2,
    const ushort* __restrict__ Wfrag, const float* __restrict__ b3,
    float* __restrict__ out, float* __restrict__ obj)
{
    __shared__ char xsb[33792];         // A quarter-tile; later params pl[64][132] f32 (exact fit)
    __shared__ float red[4];

    const int g = blockIdx.x;           // row pair: rows 2g, 2g+1
    const int b = blockIdx.y;
    const int tid = threadIdx.x;
    const int px = tid & 127;
    const int t7 = (tid >> 7) & 1;

    // ---- prologue: identity copy + transform-x prefetch (pure HBM) ----
    float xr0, xr1, xr2, xr3, xr4, xr5;
    {
        size_t base;
#define PRO(RR, KS, DST) \
        base = ((size_t)(b*CFULL + (t7 + 2*(KS)))*HH + (2*g + (RR)))*WW + px; \
        out[base] = x[base]; \
        DST = x[base + (size_t)CH*HH*WW];
        PRO(0,0,xr0) PRO(0,1,xr1) PRO(0,2,xr2)
        PRO(1,0,xr3) PRO(1,1,xr4) PRO(1,2,xr5)
#undef PRO
    }

    const int lane = tid & 63;
    const int wv   = tid >> 6;
    const int mrow = wv >> 1;           // 0..1 : which output row
    const int ncol = wv & 1;            // 0..1 : co half
    const int kg   = lane >> 4;
    const int lr   = lane & 15;

    f32x4 acc[8][2];
#pragma unroll
    for (int mf = 0; mf < 8; ++mf) {
        acc[mf][0] = (f32x4){0.f,0.f,0.f,0.f};
        acc[mf][1] = (f32x4){0.f,0.f,0.f,0.f};
    }

    const char* wbase = (const char*)Wfrag + ncol*2048 + lane*16;

#pragma unroll 1
    for (int q = 0; q < 4; ++q) {
        if (q) __syncthreads();         // protect tile from previous quarter's readers

        // ---- stage quarter: 4 h2-rows x 130 wl x 32 ci ----
        for (int i = tid; i < 2080; i += 256) {
            int r = i / 520; int rem = i - r*520;
            int wl = rem >> 2; int c4 = rem & 3;
            int hh = 2*g - 1 + r, ww = wl - 1;
            uint4 v = {0,0,0,0};
            if (hh >= 0 && hh < HH && ww >= 0 && ww < WW)
                v = *(const uint4*)&h2[(size_t)((b*HH + hh)*WW + ww)*HID + q*32 + c4*8];
            *(uint4*)(xsb + r*8448 + wl*64 + ((c4*16) ^ (((wl >> 1) & 3) << 4))) = v;
        }
        __syncthreads();

        // ---- MFMA: 9 taps, K=32 each ----
#pragma unroll 1
        for (int r3 = 0; r3 < 3; ++r3) {
            const char* rowb = xsb + (mrow + r3)*8448;
#pragma unroll
            for (int dx = 0; dx < 3; ++dx) {
                const int t = r3*3 + dx;
                const char* wp = wbase + (((t << 2) + q) << 12);
                UBF b0; b0.u = *(const uint4*)(wp);
                UBF b1; b1.u = *(const uint4*)(wp + 1024);
#pragma unroll
                for (int mf = 0; mf < 8; ++mf) {
                    const int wl = mf*16 + lr + dx;
                    UBF a; a.u = *(const uint4*)(rowb + wl*64 + ((kg*16) ^ (((wl >> 1) & 3) << 4)));
                    acc[mf][0] = __builtin_amdgcn_mfma_f32_16x16x32_bf16(a.b, b0.b, acc[mf][0], 0, 0, 0);
                    acc[mf][1] = __builtin_amdgcn_mfma_f32_16x16x32_bf16(a.b, b1.b, acc[mf][1], 0, 0, 0);
                }
            }
        }
    }
    __syncthreads();        // A-tile dead; overlay params

    float* pl = (float*)xsb;
    float lad = 0.f;

#pragma unroll
    for (int r = 0; r < 2; ++r) {
        if (r) __syncthreads();         // wait for previous phase's pl readers

        if (mrow == r) {
#pragma unroll
            for (int mf = 0; mf < 8; ++mf)
#pragma unroll
                for (int nf = 0; nf < 2; ++nf) {
                    const int co = ncol*32 + nf*16 + lr;
                    const int p0 = mf*16 + (kg << 2);
                    *(f32x4*)&pl[co*132 + p0] = acc[mf][nf];
                }
        }
        __syncthreads();

        // ---- spline for row 2g+r: 6 ch x 128 px = 768 items, 3 per thread ----
#pragma unroll
        for (int ks = 0; ks < 3; ++ks) {
            const int c = __builtin_amdgcn_readfirstlane(t7 + 2*ks);
            const float xraw = (r == 0) ? (ks == 0 ? xr0 : ks == 1 ? xr1 : xr2)
                                        : (ks == 0 ? xr3 : ks == 1 ? xr4 : xr5);

            float u[9];
#pragma unroll
            for (int j = 0; j < 9; ++j) u[j] = pl[(c*9 + j)*132 + px] + b3[c*9 + j];

            bool inside = (xraw >= -1.f) && (xraw <= 1.f);
            float xc = fminf(fmaxf(xraw, -1.f), 1.f);
            float in01 = (xc + 1.f) * 0.5f;

            float m = u[0];
#pragma unroll
            for (int i2 = 1; i2 < 5; ++i2) m = fmaxf(m, u[i2]);
            float e[5], es = 0.f;
#pragma unroll
            for (int i2 = 0; i2 < 5; ++i2) { e[i2] = expf(u[i2] - m); es += e[i2]; }
            float wdt[5];
#pragma unroll
            for (int i2 = 0; i2 < 5; ++i2) wdt[i2] = 0.001f + (1.f - 0.001f*NB) * (e[i2] / es);

            float eh[4];
#pragma unroll
            for (int i2 = 0; i2 < 4; ++i2) eh[i2] = expf(u[5 + i2]);

            float first_w = 0.5f * wdt[0], last_w = 0.5f * wdt[4];
            float numer = 0.5f*first_w*eh[0] + 0.5f*last_w*eh[3]
                        + 0.5f*(eh[0]+eh[1])*wdt[1]
                        + 0.5f*(eh[1]+eh[2])*wdt[2]
                        + 0.5f*(eh[2]+eh[3])*wdt[3];
            float cst = numer / (1.f - 0.5f*first_w - 0.5f*last_w);

            float kn[6] = {cst, eh[0], eh[1], eh[2], eh[3], cst};
            float area = 0.f;
#pragma unroll
            for (int i2 = 0; i2 < 5; ++i2) area += 0.5f*(kn[i2]+kn[i2+1])*wdt[i2];
            float hts[6];
#pragma unroll
            for (int i2 = 0; i2 < 6; ++i2) hts[i2] = 0.001f + (1.f - 0.001f) * (kn[i2] / area);

            float C[6]; C[0] = 0.f;
#pragma unroll
            for (int i2 = 0; i2 < 5; ++i2) C[i2+1] = C[i2] + 0.5f*(hts[i2]+hts[i2+1])*wdt[i2];
            C[5] = 1.f;
            float L[6]; L[0] = 0.f;
#pragma unroll
            for (int i2 = 0; i2 < 5; ++i2) L[i2+1] = L[i2] + wdt[i2];
            L[5] = 1.f;

            int idx = 0;
#pragma unroll
            for (int i2 = 1; i2 < 6; ++i2) idx += (in01 >= L[i2]) ? 1 : 0;
            idx = min(idx, 4);

            float loc = L[0], cdf = C[0], hl = hts[0], hr = hts[1], wb2 = wdt[0];
#pragma unroll
            for (int i2 = 1; i2 < 5; ++i2) {
                if (i2 == idx) { loc = L[i2]; cdf = C[i2]; hl = hts[i2]; hr = hts[i2+1]; wb2 = wdt[i2]; }
            }

            float alpha = (in01 - loc) / wb2;
            float aa = 0.5f*(hr - hl)*wb2;
            float bb = hl*wb2;
            float o = fminf(fmaxf(aa*alpha*alpha + bb*alpha + cdf, 0.f), 1.f);
            float sl = logf(alpha*(hr - hl) + hl);
            float outv = o*2.f - 1.f;
            if (!inside) { outv = xraw; sl = 0.f; }
            out[((size_t)(b*CFULL + CH + c)*HH + (2*g + r))*WW + px] = outv;
            lad += sl;
        }
    }

#pragma unroll
    for (int off = 32; off > 0; off >>= 1) lad += __shfl_down(lad, off, 64);
    if ((tid & 63) == 0) red[tid >> 6] = lad;
    __syncthreads();
    if (tid == 0) {
        float s = red[0] + red[1] + red[2] + red[3];
        atomicAdd(&obj[b], s);
    }
}

extern "C" void kernel_launch(void* const* d_in, const int* in_sizes, int n_in,
                              void* d_out, int out_size, void* d_ws, size_t ws_size,
                              hipStream_t stream) {
    const float* x   = (const float*)d_in[0];
    const float* obj = (const float*)d_in[1];
    const float* w1  = (const float*)d_in[2];
    const float* b1  = (const float*)d_in[3];
    const float* w2  = (const float*)d_in[4];
    const float* b2  = (const float*)d_in[5];
    const float* w3  = (const float*)d_in[6];
    const float* b3  = (const float*)d_in[7];

    float* out_t = (float*)d_out;
    float* obj_o = out_t + OUT_ELEMS;
    ushort* h2  = (ushort*)d_ws;
    ushort* W3f = (ushort*)((char*)d_ws + H2_BYTES);
    ushort* W1f = (ushort*)((char*)d_ws + H2_BYTES + 147456);
    ushort* W2f = (ushort*)((char*)d_ws + H2_BYTES + 147456 + 16384);

    const int prep_items = WFRAG_ELEMS + W1F_ELEMS + W2F_ELEMS;   // 98304
    k_prep_all<<<(prep_items + 255)/256, 256, 0, stream>>>(w1, w2, w3, obj, obj_o, W1f, W2f, W3f);
    k_conv12<<<B*HH, 256, 0, stream>>>(x, W1f, b1, W2f, b2, h2);
    k_conv3_spline<<<dim3(HH/2, B), 256, 0, stream>>>(x, h2, W3f, b3, out_t, obj_o);
}